// Round 6
// baseline (223.831 us; speedup 1.0000x reference)
//
#include <hip/hip_runtime.h>

// ============================================================================
// QuantumHeadAmplitude: 256 x 16-qubit statevector sim, 2 StronglyEntangling
// layers, Z-expvals, linear head.
//
// Algebra (validated R1, absmax 0.0): CNOTs are GF(2)-linear index maps,
// virtualized. stored[x] = psi_true[A^{-1} x]. A layer-1 Rot on wire w becomes
// a generalized 1q gate with XOR mask col_w(A) and role row row_w(A^{-1}).
// Expvals use final A^{-1} rows as parity masks. Normalization deferred
// (unitaries preserve norm): ev = sv/tot.
//
// R2 structure (frozen, validated): 3 passes, each = load -> register-
// resident gate stages (32 amps/thread = 5 reg bits, compile-time masks)
// -> LDS bit-exchange transposes (fp16-packed, XOR-hash banks) -> store.
//
// R7/R8: gate math via v_dot2_f32_f16. Lesson from R3-R6: v_pk_fma_f32 is
// NOT faster than scalar f32 FMA on CDNA (f32 VALU peak = 2 FLOP/lane/cy
// either way); the f32 floor itself was the wall. fdot2 does 2 f16 MACs/lane
// at full issue rate with f32 accumulate -> complex butterfly = 8 dot2 + 2
// cvt_pkrtz per pair (~20 cy) vs 32 cy at f32. State is f16x2 (re,im) per
// amp end-to-end: LDS exchanges and inter-pass HBM state move raw u32, all
// cvt at boundaries eliminated, state VGPRs halve. Addressing identical to
// the validated round-0 kernel. (R8 fix: f16x2 must be __fp16-based to match
// cvt_pkrtz/fdot2 builtin types.)
// ============================================================================

#define BATCH 256
#define NCLS 10

typedef __fp16 f16x2 __attribute__((ext_vector_type(2)));

#define KATTR __launch_bounds__(256, 4)

struct CircuitMeta { unsigned l1mask[16]; unsigned l1role[16]; unsigned fin[16]; };

__host__ __device__ constexpr CircuitMeta make_meta() {
  CircuitMeta m{};
  unsigned col[16] = {}, inv[16] = {};
  for (int w = 0; w < 16; ++w) { col[w] = 1u << (15 - w); inv[w] = 1u << (15 - w); }
  for (int w = 0; w < 16; ++w) { int c = w, t = (w + 1) & 15; col[c] ^= col[t]; inv[t] ^= inv[c]; }
  for (int w = 0; w < 16; ++w) { m.l1mask[w] = col[w]; m.l1role[w] = inv[w]; }
  for (int w = 0; w < 16; ++w) { int c = w, t = (w + 2) & 15; col[c] ^= col[t]; inv[t] ^= inv[c]; }
  for (int w = 0; w < 16; ++w) m.fin[w] = inv[w];
  return m;
}
constexpr CircuitMeta META = make_meta();

// XOR-hash for LDS bank spread (GF2-linear: HASH(a^b)=HASH(a)^HASH(b))
__host__ __device__ constexpr unsigned HASH(unsigned i) {
  return i ^ ((i >> 4) & 15u) ^ ((i >> 8) & 15u);
}

__device__ __forceinline__ float fdot2(f16x2 a, f16x2 b, float c) {
  return __builtin_amdgcn_fdot2(a, b, c, false);
}
__device__ __forceinline__ f16x2 pkh(float r, float i) {
  return __builtin_amdgcn_cvt_pkrtz(r, i);
}
__device__ __forceinline__ unsigned U32(f16x2 a) {
  return __builtin_bit_cast(unsigned, a);
}
__device__ __forceinline__ f16x2 H2(unsigned u) {
  return __builtin_bit_cast(f16x2, u);
}

template<int B0,int B1,int B2,int B3,int B4>
__host__ __device__ constexpr unsigned regval5(int j) {
  return ((unsigned)(j & 1) << B0) | ((unsigned)((j >> 1) & 1) << B1) |
         ((unsigned)((j >> 2) & 1) << B2) | ((unsigned)((j >> 3) & 1) << B3) |
         ((unsigned)((j >> 4) & 1) << B4);
}

// Generalized 1q gate, fully register-resident, f16x2 state, dot2 math.
// Reg bits B0..B4 (global bit positions for j bits 0..4). MG = XOR mask
// (covered by reg bits), RG = role row. tp = thread's non-reg bits (global).
// Role parity = parity(RG&tp) [runtime, hoisted to U-vs-XUX coefficient
// select] ^ parity(RG&regval(j)) [compile-time podd].
// Per pair: out0 = E(podd)[00] v0 + E(podd)[01] v1 ;
//           out1 = E(podd)[10] v0 + E(podd)[11] v1  (complex) ->
// 8 fdot2 (f32 accumulate) + 2 cvt_pkrtz.
template<int B0,int B1,int B2,int B3,int B4, unsigned MG, unsigned RG>
__device__ __forceinline__ void gate5(f16x2 (&A)[32], const float* __restrict__ g,
                                      int gi, unsigned tp) {
  constexpr unsigned cover = (1u<<B0)|(1u<<B1)|(1u<<B2)|(1u<<B3)|(1u<<B4);
  static_assert((MG & ~cover) == 0u, "gate mask not covered by stage reg bits");
  constexpr unsigned mr = ((MG>>B0)&1u) | (((MG>>B1)&1u)<<1) | (((MG>>B2)&1u)<<2)
                        | (((MG>>B3)&1u)<<3) | (((MG>>B4)&1u)<<4);
  static_assert(mr != 0u, "empty reg mask");
  constexpr unsigned pivot = mr & (0u - mr);

  float u00r = g[gi*8+0], u00i = g[gi*8+1], u01r = g[gi*8+2], u01i = g[gi*8+3];
  float u10r = g[gi*8+4], u10i = g[gi*8+5], u11r = g[gi*8+6], u11i = g[gi*8+7];
  const bool s = (__popc(RG & tp) & 1) != 0;   // thread-part role parity
  // E = s ? X*U*X : U  (element swap 00<->11, 01<->10)
  float e00r = s ? u11r : u00r, e00i = s ? u11i : u00i;
  float e01r = s ? u10r : u01r, e01i = s ? u10i : u01i;
  float e10r = s ? u01r : u10r, e10i = s ? u01i : u10i;
  float e11r = s ? u00r : u11r, e11i = s ? u00i : u11i;
  // dot2 coefficient registers: cXXR dotted with (re,im) gives real part,
  // cXXI gives imag part.
  f16x2 c00R = {(__fp16)e00r, (__fp16)(-e00i)};
  f16x2 c00I = {(__fp16)e00i, (__fp16)e00r};
  f16x2 c01R = {(__fp16)e01r, (__fp16)(-e01i)};
  f16x2 c01I = {(__fp16)e01i, (__fp16)e01r};
  f16x2 c10R = {(__fp16)e10r, (__fp16)(-e10i)};
  f16x2 c10I = {(__fp16)e10i, (__fp16)e10r};
  f16x2 c11R = {(__fp16)e11r, (__fp16)(-e11i)};
  f16x2 c11I = {(__fp16)e11i, (__fp16)e11r};

  #pragma unroll
  for (int j0 = 0; j0 < 32; ++j0) {
    if (j0 & (int)pivot) continue;           // canonical pair rep (folds)
    const int j1 = j0 ^ (int)mr;
    const bool podd =
      (__builtin_popcount(RG & regval5<B0,B1,B2,B3,B4>(j0)) & 1) != 0; // folds
    // positional coefficients: podd swaps roles 00<->11, 01<->10
    const f16x2 A0R = podd?c11R:c00R, A0I = podd?c11I:c00I;  // out0 <- v0
    const f16x2 A1R = podd?c10R:c01R, A1I = podd?c10I:c01I;  // out0 <- v1
    const f16x2 B0R = podd?c01R:c10R, B0I = podd?c01I:c10I;  // out1 <- v0
    const f16x2 B1R = podd?c00R:c11R, B1I = podd?c00I:c11I;  // out1 <- v1
    const f16x2 v0 = A[j0], v1 = A[j1];
    const float r0 = fdot2(v1, A1R, fdot2(v0, A0R, 0.f));
    const float i0 = fdot2(v1, A1I, fdot2(v0, A0I, 0.f));
    const float r1 = fdot2(v1, B1R, fdot2(v0, B0R, 0.f));
    const float i1 = fdot2(v1, B1I, fdot2(v0, B0I, 0.f));
    A[j0] = pkh(r0, i0);
    A[j1] = pkh(r1, i1);
  }
}

// Rot(phi,theta,omega) = RZ(omega) RY(theta) RZ(phi) -> 32 gates x 8 floats
__global__ void prep_gates(const float* __restrict__ qp, float* __restrict__ g) {
  int i = threadIdx.x;
  if (i >= 32) return;
  float phi = qp[i*3+0], th = qp[i*3+1], om = qp[i*3+2];
  float cth = cosf(0.5f*th), sth = sinf(0.5f*th);
  float a = 0.5f*(phi+om), d = 0.5f*(phi-om);
  float ca = cosf(a), sa = sinf(a), cd = cosf(d), sd = sinf(d);
  g[i*8+0] =  ca*cth; g[i*8+1] = -sa*cth;   // m00 = e^{-ia} c
  g[i*8+2] = -cd*sth; g[i*8+3] = -sd*sth;   // m01 = -e^{id} s
  g[i*8+4] =  cd*sth; g[i*8+5] = -sd*sth;   // m10 = e^{-id} s
  g[i*8+6] =  ca*cth; g[i*8+7] =  sa*cth;   // m11 = e^{ia} c
}

// ---------------------------------------------------------------------------
// PASS A: fixed global bits {15,14,13}=f, local {12..0} (packed == global).
// L0 wires 3..15 (single-bit masks, bits 12..0). Stages:
//  S1 reg {8,9,10,11,12} (load layout), S2 reg {3,4,5,6,7}, S3 reg {0,1,2,11,12}.
// ---------------------------------------------------------------------------
__global__ KATTR void passA(const float* __restrict__ x,
    unsigned* __restrict__ st, const float* __restrict__ g) {
  __shared__ unsigned L[8192];             // fp16-packed exchange buffer, 32 KB
  const int t = threadIdx.x;
  const int batch = blockIdx.x >> 3;
  const unsigned f = blockIdx.x & 7;
  const float* xb = x + ((size_t)batch << 16) + ((size_t)f << 13);

  f16x2 A[32];
  #pragma unroll
  for (int j = 0; j < 32; ++j)
    A[j] = pkh(xb[((unsigned)j << 8) | (unsigned)t], 0.f);

  // S1: wires 3..7 (bits 12..8); roles in reg bits -> tp=0
  gate5<8,9,10,11,12, 0x1000u,0x1000u>(A, g, 3, 0u);
  gate5<8,9,10,11,12, 0x0800u,0x0800u>(A, g, 4, 0u);
  gate5<8,9,10,11,12, 0x0400u,0x0400u>(A, g, 5, 0u);
  gate5<8,9,10,11,12, 0x0200u,0x0200u>(A, g, 6, 0u);
  gate5<8,9,10,11,12, 0x0100u,0x0100u>(A, g, 7, 0u);

  // Exchange S1 -> S2: write base=t rv=j<<8; read base=((t&0xF8)<<5)|(t&7) rv=j<<3
  {
    const unsigned wb = HASH((unsigned)t);
    #pragma unroll
    for (int j = 0; j < 32; ++j) L[wb ^ HASH((unsigned)j << 8)] = U32(A[j]);
    __syncthreads();
    const unsigned rb = HASH((((unsigned)t & 0xF8u) << 5) | ((unsigned)t & 7u));
    #pragma unroll
    for (int j = 0; j < 32; ++j) A[j] = H2(L[rb ^ HASH((unsigned)j << 3)]);
  }

  // S2: wires 8..12 (bits 7..3)
  gate5<3,4,5,6,7, 0x0080u,0x0080u>(A, g,  8, 0u);
  gate5<3,4,5,6,7, 0x0040u,0x0040u>(A, g,  9, 0u);
  gate5<3,4,5,6,7, 0x0020u,0x0020u>(A, g, 10, 0u);
  gate5<3,4,5,6,7, 0x0010u,0x0010u>(A, g, 11, 0u);
  gate5<3,4,5,6,7, 0x0008u,0x0008u>(A, g, 12, 0u);

  // Exchange S2 -> S3: read base=t<<3, rv=(j&7)|((j&24)<<8)
  __syncthreads();
  {
    const unsigned wb = HASH((((unsigned)t & 0xF8u) << 5) | ((unsigned)t & 7u));
    #pragma unroll
    for (int j = 0; j < 32; ++j) L[wb ^ HASH((unsigned)j << 3)] = U32(A[j]);
    __syncthreads();
    const unsigned rb = HASH((unsigned)t << 3);
    #pragma unroll
    for (int j = 0; j < 32; ++j)
      A[j] = H2(L[rb ^ HASH(((unsigned)j & 7u) | (((unsigned)j & 24u) << 8))]);
  }

  // S3: wires 13,14,15 (bits 2,1,0)
  gate5<0,1,2,11,12, 0x0004u,0x0004u>(A, g, 13, 0u);
  gate5<0,1,2,11,12, 0x0002u,0x0002u>(A, g, 14, 0u);
  gate5<0,1,2,11,12, 0x0001u,0x0001u>(A, g, 15, 0u);

  // Store fp16: amp j=jh*8+k at idx (f<<13)|(jh<<11)|(t<<3)|k -> 2 dwordx4/group
  unsigned* outb = st + ((size_t)batch << 16) + ((size_t)f << 13);
  #pragma unroll
  for (int jh = 0; jh < 4; ++jh) {
    uint4 q0, q1;
    q0.x = U32(A[jh*8+0]); q0.y = U32(A[jh*8+1]); q0.z = U32(A[jh*8+2]); q0.w = U32(A[jh*8+3]);
    q1.x = U32(A[jh*8+4]); q1.y = U32(A[jh*8+5]); q1.z = U32(A[jh*8+6]); q1.w = U32(A[jh*8+7]);
    const unsigned si = ((unsigned)jh << 11) | ((unsigned)t << 3);
    *(uint4*)(outb + si) = q0;
    *(uint4*)(outb + si + 4) = q1;
  }
}

// ---------------------------------------------------------------------------
// PASS B: fixed global bits {9,8,7}=c, local {15..10, 6..0} (packed: g>=10
// shift down 3). L0 wires 0,1,2 then L1 w={0..4, 9..15}. Stages:
//  SB1 reg g{11,12,13,14,15}, SB2 reg g{0,5,6,10,11},
//  SB3 reg g{1,2,3,4,5},      SB4 reg g{0,1,13,14,15}.
// ---------------------------------------------------------------------------
__global__ KATTR void passB(unsigned* __restrict__ st,
    const float* __restrict__ g) {
  __shared__ unsigned L[8192];
  const int t = threadIdx.x;
  const int batch = blockIdx.x >> 3;
  const unsigned c = blockIdx.x & 7;
  unsigned* stb = st + ((size_t)batch << 16);

  // SB1 load: gidx=(j<<11)|lbase; lbase: t[6:0]->g6..0, t7->g10, c->g9..7
  const unsigned lbase = ((unsigned)t & 127u) | (((unsigned)t & 128u) << 3) | (c << 7);
  f16x2 A[32];
  #pragma unroll
  for (int j = 0; j < 32; ++j) A[j] = H2(stb[((unsigned)j << 11) | lbase]);

  const unsigned tp1 = lbase;  // same bits in global space
  gate5<11,12,13,14,15, 0x8000u,0x8000u>(A, g, 0, tp1);
  gate5<11,12,13,14,15, 0x4000u,0x4000u>(A, g, 1, tp1);
  gate5<11,12,13,14,15, 0x2000u,0x2000u>(A, g, 2, tp1);
  gate5<11,12,13,14,15, META.l1mask[0], META.l1role[0]>(A, g, 16, tp1);
  gate5<11,12,13,14,15, META.l1mask[1], META.l1role[1]>(A, g, 17, tp1);
  gate5<11,12,13,14,15, META.l1mask[2], META.l1role[2]>(A, g, 18, tp1);
  gate5<11,12,13,14,15, META.l1mask[3], META.l1role[3]>(A, g, 19, tp1);

  // Exchange SB1 -> SB2 (packed space): wb=t rv=j<<8;
  // rb=((t&0xF0)<<5)|((t&15)<<1), rv=(j&1)|((j&30)<<4)
  {
    const unsigned wb = HASH((unsigned)t);
    #pragma unroll
    for (int j = 0; j < 32; ++j) L[wb ^ HASH((unsigned)j << 8)] = U32(A[j]);
    __syncthreads();
    const unsigned rb = HASH((((unsigned)t & 0xF0u) << 5) | (((unsigned)t & 15u) << 1));
    #pragma unroll
    for (int j = 0; j < 32; ++j)
      A[j] = H2(L[rb ^ HASH(((unsigned)j & 1u) | (((unsigned)j & 30u) << 4))]);
  }

  // SB2: tp: t7..t4->g15..12, t3..t0->g4..1
  const unsigned tp2 = (((unsigned)t & 0xF0u) << 8) | (((unsigned)t & 15u) << 1) | (c << 7);
  gate5<0,5,6,10,11, META.l1mask[4], META.l1role[4]>(A, g, 20, tp2);
  gate5<0,5,6,10,11, META.l1mask[9], META.l1role[9]>(A, g, 25, tp2);

  // Exchange SB2 -> SB3: rb=((t&0xFE)<<5)|(t&1), rv=j<<1
  __syncthreads();
  {
    const unsigned wb = HASH((((unsigned)t & 0xF0u) << 5) | (((unsigned)t & 15u) << 1));
    #pragma unroll
    for (int j = 0; j < 32; ++j)
      L[wb ^ HASH(((unsigned)j & 1u) | (((unsigned)j & 30u) << 4))] = U32(A[j]);
    __syncthreads();
    const unsigned rb = HASH((((unsigned)t & 0xFEu) << 5) | ((unsigned)t & 1u));
    #pragma unroll
    for (int j = 0; j < 32; ++j) A[j] = H2(L[rb ^ HASH((unsigned)j << 1)]);
  }

  // SB3: tp: t7..t2->g15..g10, t1->g6, t0->g0
  const unsigned tp3 = (((unsigned)t & 0xFCu) << 8) | (((unsigned)t & 2u) << 5)
                     | ((unsigned)t & 1u) | (c << 7);
  gate5<1,2,3,4,5, META.l1mask[10], META.l1role[10]>(A, g, 26, tp3);
  gate5<1,2,3,4,5, META.l1mask[11], META.l1role[11]>(A, g, 27, tp3);
  gate5<1,2,3,4,5, META.l1mask[12], META.l1role[12]>(A, g, 28, tp3);
  gate5<1,2,3,4,5, META.l1mask[13], META.l1role[13]>(A, g, 29, tp3);

  // Exchange SB3 -> SB4: rb=t<<2, rv=(j&3)|((j&28)<<8) (packed bits {0,1,10,11,12})
  __syncthreads();
  {
    const unsigned wb = HASH((((unsigned)t & 0xFEu) << 5) | ((unsigned)t & 1u));
    #pragma unroll
    for (int j = 0; j < 32; ++j) L[wb ^ HASH((unsigned)j << 1)] = U32(A[j]);
    __syncthreads();
    const unsigned rb = HASH((unsigned)t << 2);
    #pragma unroll
    for (int j = 0; j < 32; ++j)
      A[j] = H2(L[rb ^ HASH(((unsigned)j & 3u) | (((unsigned)j & 28u) << 8))]);
  }

  // SB4: tp: t7..t5->g12..g10, t4..t0->g6..g2
  const unsigned tp4 = (((unsigned)t & 0xE0u) << 5) | (((unsigned)t & 31u) << 2) | (c << 7);
  gate5<0,1,13,14,15, META.l1mask[14], META.l1role[14]>(A, g, 30, tp4);
  gate5<0,1,13,14,15, META.l1mask[15], META.l1role[15]>(A, g, 31, tp4);

  // Store: amp j=jh*4+k at gidx = tp4 | (jh<<13) | k -> dwordx4
  #pragma unroll
  for (int jh = 0; jh < 8; ++jh) {
    uint4 q;
    q.x = U32(A[jh*4+0]); q.y = U32(A[jh*4+1]); q.z = U32(A[jh*4+2]); q.w = U32(A[jh*4+3]);
    *(uint4*)(stb + (tp4 | ((unsigned)jh << 13))) = q;
  }
}

// ---------------------------------------------------------------------------
// PASS C: fixed {15,14,13}=f, local {12..0}. Reg {6,7,8,9,10}: L1 w=5,6,7,8.
// Then fused Z-expvals with compile-time reg signs + hoisted thread signs.
// ---------------------------------------------------------------------------
__global__ KATTR void passC(const unsigned* __restrict__ st,
    const float* __restrict__ g, float* __restrict__ partials) {
  __shared__ float R[4][17];
  const int t = threadIdx.x;
  const int batch = blockIdx.x >> 3;
  const unsigned f = blockIdx.x & 7;
  const unsigned* stb = st + ((size_t)batch << 16);

  // cbase: f->g15..13, t7,t6->g12,g11, t5..t0->g5..0 ; j->g10..6
  const unsigned cbase = (f << 13) | (((unsigned)t & 192u) << 5) | ((unsigned)t & 63u);
  f16x2 A[32];
  #pragma unroll
  for (int j = 0; j < 32; ++j) A[j] = H2(stb[cbase | ((unsigned)j << 6)]);

  gate5<6,7,8,9,10, META.l1mask[5], META.l1role[5]>(A, g, 21, cbase);
  gate5<6,7,8,9,10, META.l1mask[6], META.l1role[6]>(A, g, 22, cbase);
  gate5<6,7,8,9,10, META.l1mask[7], META.l1role[7]>(A, g, 23, cbase);
  gate5<6,7,8,9,10, META.l1mask[8], META.l1role[8]>(A, g, 24, cbase);

  float sv[16], tot = 0.f;
  #pragma unroll
  for (int w = 0; w < 16; ++w) sv[w] = 0.f;
  #pragma unroll
  for (int j = 0; j < 32; ++j) {
    const float pr = fdot2(A[j], A[j], 0.f);   // |amp|^2, f32 accumulate
    tot += pr;
    #pragma unroll
    for (int w = 0; w < 16; ++w) {
      const bool neg = (__builtin_popcount(META.fin[w] & ((unsigned)j << 6)) & 1) != 0; // folds
      sv[w] += neg ? -pr : pr;
    }
  }
  #pragma unroll
  for (int w = 0; w < 16; ++w)
    if (__popc(META.fin[w] & cbase) & 1) sv[w] = -sv[w];   // thread-part sign

  #pragma unroll
  for (int off = 32; off; off >>= 1) {
    tot += __shfl_xor(tot, off, 64);
    #pragma unroll
    for (int w = 0; w < 16; ++w) sv[w] += __shfl_xor(sv[w], off, 64);
  }
  const int wave = t >> 6, lane = t & 63;
  if (lane == 0) {
    #pragma unroll
    for (int w = 0; w < 16; ++w) R[wave][w] = sv[w];
    R[wave][16] = tot;
  }
  __syncthreads();
  if (t < 17) {
    const float s2 = R[0][t] + R[1][t] + R[2][t] + R[3][t];
    partials[(size_t)blockIdx.x * 17 + t] = s2;
  }
}

__global__ __launch_bounds__(64) void head(const float* __restrict__ partials,
    const float* __restrict__ W, const float* __restrict__ bias,
    float* __restrict__ out) {
  const int b = blockIdx.x, tid = threadIdx.x;
  __shared__ float red[17];
  __shared__ float ev[16];
  if (tid < 17) {
    float s = 0.f;
    #pragma unroll
    for (int ch = 0; ch < 8; ++ch) s += partials[(size_t)((b << 3) + ch) * 17 + tid];
    red[tid] = s;
  }
  __syncthreads();
  if (tid < 16) ev[tid] = red[tid] / red[16];
  __syncthreads();
  if (tid < NCLS) {
    float o = bias[tid];
    #pragma unroll
    for (int w = 0; w < 16; ++w) o += ev[w] * W[tid*16 + w];
    out[b*NCLS + tid] = o;
  }
}

extern "C" void kernel_launch(void* const* d_in, const int* in_sizes, int n_in,
                              void* d_out, int out_size, void* d_ws, size_t ws_size,
                              hipStream_t stream) {
  const float* x  = (const float*)d_in[0];   // (256, 65536)
  const float* qp = (const float*)d_in[1];   // (2,16,3)
  const float* W  = (const float*)d_in[2];   // (10,16)
  const float* bv = (const float*)d_in[3];   // (10,)
  float* out = (float*)d_out;                // (256,10) fp32

  // ws: fp16 state (64 MB) | gates (1 KB) | partials (2048*17 floats)
  unsigned* st     = (unsigned*)d_ws;
  float*    gates  = (float*)((char*)d_ws + (size_t)BATCH * 65536 * 4);
  float*    parts  = (float*)((char*)gates + 1024);

  prep_gates<<<dim3(1), dim3(64), 0, stream>>>(qp, gates);
  passA<<<dim3(BATCH*8), dim3(256), 0, stream>>>(x, st, gates);
  passB<<<dim3(BATCH*8), dim3(256), 0, stream>>>(st, gates);
  passC<<<dim3(BATCH*8), dim3(256), 0, stream>>>(st, gates, parts);
  head<<<dim3(BATCH), dim3(64), 0, stream>>>(parts, W, bv, out);
}

// Round 7
// 190.435 us; speedup vs baseline: 1.1754x; 1.1754x over previous
//
#include <hip/hip_runtime.h>

// ============================================================================
// QuantumHeadAmplitude: 256 x 16-qubit statevector sim, 2 StronglyEntangling
// layers, Z-expvals, linear head.
//
// Algebra (validated R1, absmax 0.0): CNOTs are GF(2)-linear index maps,
// virtualized. stored[x] = psi_true[A^{-1} x]. A layer-1 Rot on wire w becomes
// a generalized 1q gate with XOR mask col_w(A) and role row row_w(A^{-1}).
// Expvals use final A^{-1} rows as parity masks. Normalization deferred.
//
// R2 structure (frozen): 3 passes, each = load -> register-resident gate
// stages (32 amps/thread = 5 reg bits) -> LDS bit-exchange transposes
// (fp16-packed AoS, XOR-hash banks) -> store. Inter-pass state fp16.
//
// R6 (validated, 203.7us): state as lane-packed SoA pairs Vr[16]/Vi[16];
// packed lane = one stage reg bit; butterfly = 16 packed fma per k-pair,
// no re/im swaps. Branch invariants static_asserted.
//
// R9: element type f32 -> f16 in the R6 structure. Measured gfx950 VALU
// costs: v_fma_f32 2cy/2FLOP; v_pk_fma_f32 4cy (R4/R6 null); v_dot2_f32_f16
// ~4cy (R8 regression). Only v_pk_fma_f16 (2cy, 2 MACs) beats the f32
// floor -> halves gate-math cycles. SoA form needs no op_sel/swaps; AoS
// (re,im)-u32 LDS/HBM layout kept, SoA<->AoS via half extracts at edges.
// ============================================================================

#define BATCH 256
#define NCLS 10

typedef _Float16 h2 __attribute__((ext_vector_type(2)));
typedef float v2f __attribute__((ext_vector_type(2)));

#define KATTR __launch_bounds__(256, 4)

struct CircuitMeta { unsigned l1mask[16]; unsigned l1role[16]; unsigned fin[16]; };

__host__ __device__ constexpr CircuitMeta make_meta() {
  CircuitMeta m{};
  unsigned col[16] = {}, inv[16] = {};
  for (int w = 0; w < 16; ++w) { col[w] = 1u << (15 - w); inv[w] = 1u << (15 - w); }
  for (int w = 0; w < 16; ++w) { int c = w, t = (w + 1) & 15; col[c] ^= col[t]; inv[t] ^= inv[c]; }
  for (int w = 0; w < 16; ++w) { m.l1mask[w] = col[w]; m.l1role[w] = inv[w]; }
  for (int w = 0; w < 16; ++w) { int c = w, t = (w + 2) & 15; col[c] ^= col[t]; inv[t] ^= inv[c]; }
  for (int w = 0; w < 16; ++w) m.fin[w] = inv[w];
  return m;
}
constexpr CircuitMeta META = make_meta();

// XOR-hash for LDS bank spread (GF2-linear: HASH(a^b)=HASH(a)^HASH(b))
__host__ __device__ constexpr unsigned HASH(unsigned i) {
  return i ^ ((i >> 4) & 15u) ^ ((i >> 8) & 15u);
}

__device__ __forceinline__ h2 hfma(h2 a, h2 b, h2 c) {
  return __builtin_elementwise_fma(a, b, c);
}
__device__ __forceinline__ h2 hswp(h2 a) { return __builtin_shufflevector(a, a, 1, 0); }
__device__ __forceinline__ v2f vfma(v2f a, v2f b, v2f c) {
  return __builtin_elementwise_fma(a, b, c);
}
__device__ __forceinline__ unsigned U32(h2 a) { return __builtin_bit_cast(unsigned, a); }
__device__ __forceinline__ h2 H2(unsigned u) { return __builtin_bit_cast(h2, u); }
// AoS amp (re,im) of packed lane l (l is unroll-constant)
__device__ __forceinline__ unsigned AMPU(h2 r, h2 i, int l) {
  h2 a = l ? (h2){r.y, i.y} : (h2){r.x, i.x};
  return U32(a);
}

// E(q)_pos with pos: 0=00,1=01,2=10,3=11 ; q=1 applies XUX (00<->11, 01<->10).
__device__ __forceinline__ float esel(int q, int pos, float e00, float e01,
                                      float e10, float e11) {
  int p = q ? 3 - pos : pos;
  return p == 0 ? e00 : p == 1 ? e01 : p == 2 ? e10 : e11;
}

// ---------------------------------------------------------------------------
// Generalized 1q gate on persistent h2 SoA state. KB0..KB3 = global bits of
// the 4 k-index bits, LB = global bit of the packed lane. MG = XOR mask
// (covered by {KB*,LB}), RG = role row. tp = thread's non-reg bits (global).
// Element role parity q = parity(RG&tp) [in E via s] ^ parity(rk&k) ^ rl*l.
// Uniform rule: new[x] = ER(q,0)*x + ER(q,1)*partner.   (validated R6)
// ---------------------------------------------------------------------------
template<int KB0,int KB1,int KB2,int KB3,int LB, unsigned MG, unsigned RG>
__device__ __forceinline__ void gateV(h2 (&Vr)[16], h2 (&Vi)[16],
                                      const float* __restrict__ g,
                                      int gi, unsigned tp) {
  constexpr unsigned cover = (1u<<KB0)|(1u<<KB1)|(1u<<KB2)|(1u<<KB3)|(1u<<LB);
  static_assert((MG & ~cover) == 0u, "gate mask not covered by stage reg bits");
  constexpr unsigned mk = ((MG>>KB0)&1u) | (((MG>>KB1)&1u)<<1)
                        | (((MG>>KB2)&1u)<<2) | (((MG>>KB3)&1u)<<3);
  constexpr int ml = (int)((MG>>LB)&1u);
  constexpr unsigned rk = ((RG>>KB0)&1u) | (((RG>>KB1)&1u)<<1)
                        | (((RG>>KB2)&1u)<<2) | (((RG>>KB3)&1u)<<3);
  constexpr int rl = (int)((RG>>LB)&1u);
  static_assert(mk != 0u || ml != 0, "empty mask");

  float u00r = g[gi*8+0], u00i = g[gi*8+1], u01r = g[gi*8+2], u01i = g[gi*8+3];
  float u10r = g[gi*8+4], u10i = g[gi*8+5], u11r = g[gi*8+6], u11i = g[gi*8+7];
  const bool s = (__popc(RG & tp) & 1) != 0;   // thread-part role parity
  float e00r = s?u11r:u00r, e00i = s?u11i:u00i;
  float e01r = s?u10r:u01r, e01i = s?u10i:u01i;
  float e10r = s?u01r:u10r, e10i = s?u01i:u10i;
  float e11r = s?u00r:u11r, e11i = s?u00i:u11i;
  #define ER(q,pos) (_Float16)esel((q),(pos),e00r,e01r,e10r,e11r)
  #define EI(q,pos) (_Float16)esel((q),(pos),e00i,e01i,e10i,e11i)

  if constexpr (ml == 0) {
    // -------- packed gate: butterfly across h2 regs, lanes aligned ---------
    static_assert((__builtin_popcount(rk & mk) & 1) == 1, "pair parity invariant");
    h2 c00r = {ER(0,0), ER(rl,0)}, c00i = {EI(0,0), EI(rl,0)};
    h2 c01r = {ER(0,1), ER(rl,1)}, c01i = {EI(0,1), EI(rl,1)};
    h2 c10r = {ER(0,2), ER(rl,2)}, c10i = {EI(0,2), EI(rl,2)};
    h2 c11r = {ER(0,3), ER(rl,3)}, c11i = {EI(0,3), EI(rl,3)};
    constexpr unsigned pivot = mk & (0u - mk);
    #pragma unroll
    for (int k0 = 0; k0 < 16; ++k0) {
      if (k0 & (int)pivot) continue;
      const int k1 = k0 ^ (int)mk;
      const bool podd = (__builtin_popcount(rk & (unsigned)k0) & 1) != 0; // folds
      const h2 A0r = podd?c11r:c00r, A0i = podd?c11i:c00i;  // out0 <- v0
      const h2 A1r = podd?c10r:c01r, A1i = podd?c10i:c01i;  // out0 <- v1
      const h2 B0r = podd?c01r:c10r, B0i = podd?c01i:c10i;  // out1 <- v0
      const h2 B1r = podd?c00r:c11r, B1i = podd?c00i:c11i;  // out1 <- v1
      const h2 v0r = Vr[k0], v0i = Vi[k0], v1r = Vr[k1], v1i = Vi[k1];
      h2 n0r = A0r*v0r; n0r = hfma(-A0i, v0i, n0r);
      n0r = hfma(A1r, v1r, n0r); n0r = hfma(-A1i, v1i, n0r);
      h2 n0i = A0r*v0i; n0i = hfma(A0i, v0r, n0i);
      n0i = hfma(A1r, v1i, n0i); n0i = hfma(A1i, v1r, n0i);
      h2 n1r = B0r*v0r; n1r = hfma(-B0i, v0i, n1r);
      n1r = hfma(B1r, v1r, n1r); n1r = hfma(-B1i, v1i, n1r);
      h2 n1i = B0r*v0i; n1i = hfma(B0i, v0r, n1i);
      n1i = hfma(B1r, v1i, n1i); n1i = hfma(B1i, v1r, n1i);
      Vr[k0] = n0r; Vi[k0] = n0i; Vr[k1] = n1r; Vi[k1] = n1i;
    }
  } else if constexpr (mk == 0u) {
    // -------- lane-only gate: 2x2 matvec inside each h2 -------------------
    static_assert(rl == 1, "lane-only gate requires rl==1");
    h2 CA0r = {ER(0,0), ER(1,0)}, CA0i = {EI(0,0), EI(1,0)};
    h2 CB0r = {ER(0,1), ER(1,1)}, CB0i = {EI(0,1), EI(1,1)};
    h2 CA1r = {ER(1,0), ER(0,0)}, CA1i = {EI(1,0), EI(0,0)};
    h2 CB1r = {ER(1,1), ER(0,1)}, CB1i = {EI(1,1), EI(0,1)};
    #pragma unroll
    for (int k = 0; k < 16; ++k) {
      const bool q = (__builtin_popcount(rk & (unsigned)k) & 1) != 0; // folds
      const h2 CAr = q?CA1r:CA0r, CAi = q?CA1i:CA0i;
      const h2 CBr = q?CB1r:CB0r, CBi = q?CB1i:CB0i;
      const h2 vr = Vr[k], vi = Vi[k];
      const h2 svr = hswp(vr), svi = hswp(vi);
      h2 nr = CAr*vr; nr = hfma(-CAi, vi, nr);
      nr = hfma(CBr, svr, nr); nr = hfma(-CBi, svi, nr);
      h2 ni = CAr*vi; ni = hfma(CAi, vr, ni);
      ni = hfma(CBr, svi, ni); ni = hfma(CBi, svr, ni);
      Vr[k] = nr; Vi[k] = ni;
    }
  } else {
    // -------- cross gate: mask = lane + k bits ----------------------------
    constexpr int dm = __builtin_popcount(rk & mk) & 1;
    static_assert((dm ^ rl) == 1, "cross gate pair parity invariant");
    h2 CA0r = {ER(0,0), ER(rl,0)},          CA0i = {EI(0,0), EI(rl,0)};
    h2 CB0r = {ER(0,1), ER(rl,1)},          CB0i = {EI(0,1), EI(rl,1)};
    h2 CC0r = {ER(dm,0), ER(dm^rl,0)},      CC0i = {EI(dm,0), EI(dm^rl,0)};
    h2 CD0r = {ER(dm,1), ER(dm^rl,1)},      CD0i = {EI(dm,1), EI(dm^rl,1)};
    h2 CA1r = {ER(1,0), ER(1^rl,0)},        CA1i = {EI(1,0), EI(1^rl,0)};
    h2 CB1r = {ER(1,1), ER(1^rl,1)},        CB1i = {EI(1,1), EI(1^rl,1)};
    h2 CC1r = {ER(1^dm,0), ER(1^dm^rl,0)},  CC1i = {EI(1^dm,0), EI(1^dm^rl,0)};
    h2 CD1r = {ER(1^dm,1), ER(1^dm^rl,1)},  CD1i = {EI(1^dm,1), EI(1^dm^rl,1)};
    constexpr unsigned pivot = mk & (0u - mk);
    #pragma unroll
    for (int k0 = 0; k0 < 16; ++k0) {
      if (k0 & (int)pivot) continue;
      const int k1 = k0 ^ (int)mk;
      const bool q = (__builtin_popcount(rk & (unsigned)k0) & 1) != 0; // folds
      const h2 CAr = q?CA1r:CA0r, CAi = q?CA1i:CA0i;
      const h2 CBr = q?CB1r:CB0r, CBi = q?CB1i:CB0i;
      const h2 CCr = q?CC1r:CC0r, CCi = q?CC1i:CC0i;
      const h2 CDr = q?CD1r:CD0r, CDi = q?CD1i:CD0i;
      const h2 vr = Vr[k0], vi = Vi[k0], ur = Vr[k1], ui = Vi[k1];
      const h2 sur = hswp(ur), sui = hswp(ui), svr = hswp(vr), svi = hswp(vi);
      h2 nvr = CAr*vr; nvr = hfma(-CAi, vi, nvr);
      nvr = hfma(CBr, sur, nvr); nvr = hfma(-CBi, sui, nvr);
      h2 nvi = CAr*vi; nvi = hfma(CAi, vr, nvi);
      nvi = hfma(CBr, sui, nvi); nvi = hfma(CBi, sur, nvi);
      h2 nur = CCr*ur; nur = hfma(-CCi, ui, nur);
      nur = hfma(CDr, svr, nur); nur = hfma(-CDi, svi, nur);
      h2 nui = CCr*ui; nui = hfma(CCi, ur, nui);
      nui = hfma(CDr, svi, nui); nui = hfma(CDi, svr, nui);
      Vr[k0] = nvr; Vi[k0] = nvi; Vr[k1] = nur; Vi[k1] = nui;
    }
  }
  #undef ER
  #undef EI
}

// Rot(phi,theta,omega) = RZ(omega) RY(theta) RZ(phi) -> 32 gates x 8 floats
__global__ void prep_gates(const float* __restrict__ qp, float* __restrict__ g) {
  int i = threadIdx.x;
  if (i >= 32) return;
  float phi = qp[i*3+0], th = qp[i*3+1], om = qp[i*3+2];
  float cth = cosf(0.5f*th), sth = sinf(0.5f*th);
  float a = 0.5f*(phi+om), d = 0.5f*(phi-om);
  float ca = cosf(a), sa = sinf(a), cd = cosf(d), sd = sinf(d);
  g[i*8+0] =  ca*cth; g[i*8+1] = -sa*cth;   // m00 = e^{-ia} c
  g[i*8+2] = -cd*sth; g[i*8+3] = -sd*sth;   // m01 = -e^{id} s
  g[i*8+4] =  cd*sth; g[i*8+5] = -sd*sth;   // m10 = e^{-id} s
  g[i*8+6] =  ca*cth; g[i*8+7] =  sa*cth;   // m11 = e^{ia} c
}

// ---------------------------------------------------------------------------
// PASS A: fixed global bits {15,14,13}=f, local {12..0}.
// L0 wires 3..15. Stages (lane bit chosen out of masks where possible):
//  S1: k->{9,10,11,12}, lane=8  (w3..w6 packed, w7 lane-only)
//  S2: k->{4,5,6,7},   lane=3  (w8..w11 packed, w12 lane-only)
//  S3: k->{0,1,2,11},  lane=12 (w13..w15 packed)
// ---------------------------------------------------------------------------
__global__ KATTR void passA(const float* __restrict__ x,
    unsigned* __restrict__ st, const float* __restrict__ g) {
  __shared__ unsigned L[8192];             // fp16-packed exchange buffer, 32 KB
  const int t = threadIdx.x;
  const int batch = blockIdx.x >> 3;
  const unsigned f = blockIdx.x & 7;
  const float* xb = x + ((size_t)batch << 16) + ((size_t)f << 13);

  h2 Vr[16], Vi[16];
  #pragma unroll
  for (int k = 0; k < 16; ++k) {
    Vr[k] = (h2){(_Float16)xb[((unsigned)k << 9) | (unsigned)t],
                 (_Float16)xb[((unsigned)k << 9) | 256u | (unsigned)t]};
    Vi[k] = (h2){(_Float16)0.f, (_Float16)0.f};
  }

  // S1: wires 3..7 (bits 12..8); roles in reg bits -> tp=0
  gateV<9,10,11,12,8, 0x1000u,0x1000u>(Vr, Vi, g, 3, 0u);
  gateV<9,10,11,12,8, 0x0800u,0x0800u>(Vr, Vi, g, 4, 0u);
  gateV<9,10,11,12,8, 0x0400u,0x0400u>(Vr, Vi, g, 5, 0u);
  gateV<9,10,11,12,8, 0x0200u,0x0200u>(Vr, Vi, g, 6, 0u);
  gateV<9,10,11,12,8, 0x0100u,0x0100u>(Vr, Vi, g, 7, 0u);   // lane-only

  // Exchange S1 -> S2 (identical LDS slots as R2/R6)
  {
    const unsigned wb = HASH((unsigned)t);
    #pragma unroll
    for (int k = 0; k < 16; ++k) {
      L[wb ^ HASH(((unsigned)k << 9))]        = AMPU(Vr[k], Vi[k], 0);
      L[wb ^ HASH(((unsigned)k << 9) | 256u)] = AMPU(Vr[k], Vi[k], 1);
    }
    __syncthreads();
    const unsigned rb = HASH((((unsigned)t & 0xF8u) << 5) | ((unsigned)t & 7u));
    #pragma unroll
    for (int k = 0; k < 16; ++k) {
      h2 h0 = H2(L[rb ^ HASH(((unsigned)k << 4))]);
      h2 h1 = H2(L[rb ^ HASH(((unsigned)k << 4) | 8u)]);
      Vr[k] = (h2){h0.x, h1.x};
      Vi[k] = (h2){h0.y, h1.y};
    }
  }

  // S2: wires 8..12 (bits 7..3)
  gateV<4,5,6,7,3, 0x0080u,0x0080u>(Vr, Vi, g,  8, 0u);
  gateV<4,5,6,7,3, 0x0040u,0x0040u>(Vr, Vi, g,  9, 0u);
  gateV<4,5,6,7,3, 0x0020u,0x0020u>(Vr, Vi, g, 10, 0u);
  gateV<4,5,6,7,3, 0x0010u,0x0010u>(Vr, Vi, g, 11, 0u);
  gateV<4,5,6,7,3, 0x0008u,0x0008u>(Vr, Vi, g, 12, 0u);     // lane-only

  // Exchange S2 -> S3
  __syncthreads();
  {
    const unsigned wb = HASH((((unsigned)t & 0xF8u) << 5) | ((unsigned)t & 7u));
    #pragma unroll
    for (int k = 0; k < 16; ++k) {
      L[wb ^ HASH(((unsigned)k << 4))]      = AMPU(Vr[k], Vi[k], 0);
      L[wb ^ HASH(((unsigned)k << 4) | 8u)] = AMPU(Vr[k], Vi[k], 1);
    }
    __syncthreads();
    const unsigned rb = HASH((unsigned)t << 3);
    #pragma unroll
    for (int k = 0; k < 16; ++k) {
      const unsigned kv = ((unsigned)k & 7u) | (((unsigned)k & 8u) << 8);
      h2 h0 = H2(L[rb ^ HASH(kv)]);
      h2 h1 = H2(L[rb ^ HASH(kv | 4096u)]);
      Vr[k] = (h2){h0.x, h1.x};
      Vi[k] = (h2){h0.y, h1.y};
    }
  }

  // S3: wires 13,14,15 (bits 2,1,0); lane=12 untouched by masks
  gateV<0,1,2,11,12, 0x0004u,0x0004u>(Vr, Vi, g, 13, 0u);
  gateV<0,1,2,11,12, 0x0002u,0x0002u>(Vr, Vi, g, 14, 0u);
  gateV<0,1,2,11,12, 0x0001u,0x0001u>(Vr, Vi, g, 15, 0u);

  // Store fp16: amp(k,l) at idx (l<<12)|((k>>3)<<11)|(t<<3)|(k&7)
  unsigned* outb = st + ((size_t)batch << 16) + ((size_t)f << 13);
  #pragma unroll
  for (int l = 0; l < 2; ++l) {
    #pragma unroll
    for (int kh = 0; kh < 2; ++kh) {
      uint4 q0, q1;
      q0.x = AMPU(Vr[kh*8+0], Vi[kh*8+0], l); q0.y = AMPU(Vr[kh*8+1], Vi[kh*8+1], l);
      q0.z = AMPU(Vr[kh*8+2], Vi[kh*8+2], l); q0.w = AMPU(Vr[kh*8+3], Vi[kh*8+3], l);
      q1.x = AMPU(Vr[kh*8+4], Vi[kh*8+4], l); q1.y = AMPU(Vr[kh*8+5], Vi[kh*8+5], l);
      q1.z = AMPU(Vr[kh*8+6], Vi[kh*8+6], l); q1.w = AMPU(Vr[kh*8+7], Vi[kh*8+7], l);
      const unsigned si = ((unsigned)l << 12) | ((unsigned)kh << 11) | ((unsigned)t << 3);
      *(uint4*)(outb + si) = q0;
      *(uint4*)(outb + si + 4) = q1;
    }
  }
}

// ---------------------------------------------------------------------------
// PASS B: fixed global bits {9,8,7}=c, local {15..10, 6..0} (packed: g>=10
// shift down 3). Stages:
//  SB1: k->{12,13,14,15}, lane=11 (w0,w1,w2, gi16..18 packed; gi19 cross)
//  SB2: k->{5,6,10,11},   lane=0  (gi20, gi25 packed)
//  SB3: k->{2,3,4,5},     lane=1  (gi26..28 packed; gi29 cross)
//  SB4: k->{0,1,14,15},   lane=13 (gi30, gi31 packed, per-lane roles)
// ---------------------------------------------------------------------------
__global__ KATTR void passB(unsigned* __restrict__ st,
    const float* __restrict__ g) {
  __shared__ unsigned L[8192];
  const int t = threadIdx.x;
  const int batch = blockIdx.x >> 3;
  const unsigned c = blockIdx.x & 7;
  unsigned* stb = st + ((size_t)batch << 16);

  // SB1 load: lbase: t[6:0]->g6..0, t7->g10, c->g9..7 ; k->g15..12, l->g11
  const unsigned lbase = ((unsigned)t & 127u) | (((unsigned)t & 128u) << 3) | (c << 7);
  h2 Vr[16], Vi[16];
  #pragma unroll
  for (int k = 0; k < 16; ++k) {
    h2 h0 = H2(stb[((unsigned)k << 12) | lbase]);
    h2 h1 = H2(stb[((unsigned)k << 12) | 2048u | lbase]);
    Vr[k] = (h2){h0.x, h1.x};
    Vi[k] = (h2){h0.y, h1.y};
  }

  const unsigned tp1 = lbase;
  gateV<12,13,14,15,11, 0x8000u,0x8000u>(Vr, Vi, g, 0, tp1);
  gateV<12,13,14,15,11, 0x4000u,0x4000u>(Vr, Vi, g, 1, tp1);
  gateV<12,13,14,15,11, 0x2000u,0x2000u>(Vr, Vi, g, 2, tp1);
  gateV<12,13,14,15,11, META.l1mask[0], META.l1role[0]>(Vr, Vi, g, 16, tp1);
  gateV<12,13,14,15,11, META.l1mask[1], META.l1role[1]>(Vr, Vi, g, 17, tp1);
  gateV<12,13,14,15,11, META.l1mask[2], META.l1role[2]>(Vr, Vi, g, 18, tp1);
  gateV<12,13,14,15,11, META.l1mask[3], META.l1role[3]>(Vr, Vi, g, 19, tp1); // cross

  // Exchange SB1 -> SB2 (packed space): identical slots as R2/R6
  {
    const unsigned wb = HASH((unsigned)t);
    #pragma unroll
    for (int k = 0; k < 16; ++k) {
      L[wb ^ HASH(((unsigned)k << 9))]        = AMPU(Vr[k], Vi[k], 0);
      L[wb ^ HASH(((unsigned)k << 9) | 256u)] = AMPU(Vr[k], Vi[k], 1);
    }
    __syncthreads();
    const unsigned rb = HASH((((unsigned)t & 0xF0u) << 5) | (((unsigned)t & 15u) << 1));
    #pragma unroll
    for (int k = 0; k < 16; ++k) {
      h2 h0 = H2(L[rb ^ HASH(((unsigned)k << 5))]);
      h2 h1 = H2(L[rb ^ HASH(((unsigned)k << 5) | 1u)]);
      Vr[k] = (h2){h0.x, h1.x};
      Vi[k] = (h2){h0.y, h1.y};
    }
  }

  // SB2: k->{5,6,10,11}, lane=0 ; tp: t7..t4->g15..12, t3..t0->g4..1
  const unsigned tp2 = (((unsigned)t & 0xF0u) << 8) | (((unsigned)t & 15u) << 1) | (c << 7);
  gateV<5,6,10,11,0, META.l1mask[4], META.l1role[4]>(Vr, Vi, g, 20, tp2);
  gateV<5,6,10,11,0, META.l1mask[9], META.l1role[9]>(Vr, Vi, g, 25, tp2);

  // Exchange SB2 -> SB3
  __syncthreads();
  {
    const unsigned wb = HASH((((unsigned)t & 0xF0u) << 5) | (((unsigned)t & 15u) << 1));
    #pragma unroll
    for (int k = 0; k < 16; ++k) {
      L[wb ^ HASH(((unsigned)k << 5))]      = AMPU(Vr[k], Vi[k], 0);
      L[wb ^ HASH(((unsigned)k << 5) | 1u)] = AMPU(Vr[k], Vi[k], 1);
    }
    __syncthreads();
    const unsigned rb = HASH((((unsigned)t & 0xFEu) << 5) | ((unsigned)t & 1u));
    #pragma unroll
    for (int k = 0; k < 16; ++k) {
      h2 h0 = H2(L[rb ^ HASH(((unsigned)k << 2))]);
      h2 h1 = H2(L[rb ^ HASH(((unsigned)k << 2) | 2u)]);
      Vr[k] = (h2){h0.x, h1.x};
      Vi[k] = (h2){h0.y, h1.y};
    }
  }

  // SB3: k->{2,3,4,5}, lane=1 ; tp: t7..t2->g15..g10, t1->g6, t0->g0
  const unsigned tp3 = (((unsigned)t & 0xFCu) << 8) | (((unsigned)t & 2u) << 5)
                     | ((unsigned)t & 1u) | (c << 7);
  gateV<2,3,4,5,1, META.l1mask[10], META.l1role[10]>(Vr, Vi, g, 26, tp3);
  gateV<2,3,4,5,1, META.l1mask[11], META.l1role[11]>(Vr, Vi, g, 27, tp3);
  gateV<2,3,4,5,1, META.l1mask[12], META.l1role[12]>(Vr, Vi, g, 28, tp3);
  gateV<2,3,4,5,1, META.l1mask[13], META.l1role[13]>(Vr, Vi, g, 29, tp3); // cross

  // Exchange SB3 -> SB4
  __syncthreads();
  {
    const unsigned wb = HASH((((unsigned)t & 0xFEu) << 5) | ((unsigned)t & 1u));
    #pragma unroll
    for (int k = 0; k < 16; ++k) {
      L[wb ^ HASH(((unsigned)k << 2))]      = AMPU(Vr[k], Vi[k], 0);
      L[wb ^ HASH(((unsigned)k << 2) | 2u)] = AMPU(Vr[k], Vi[k], 1);
    }
    __syncthreads();
    const unsigned rb = HASH((unsigned)t << 2);
    #pragma unroll
    for (int k = 0; k < 16; ++k) {
      const unsigned kv = ((unsigned)k & 3u) | (((unsigned)k & 12u) << 9);
      h2 h0 = H2(L[rb ^ HASH(kv)]);
      h2 h1 = H2(L[rb ^ HASH(kv | 1024u)]);
      Vr[k] = (h2){h0.x, h1.x};
      Vi[k] = (h2){h0.y, h1.y};
    }
  }

  // SB4: k->{0,1,14,15}, lane=13 ; tp: t7..t5->g12..g10, t4..t0->g6..g2
  const unsigned tp4 = (((unsigned)t & 0xE0u) << 5) | (((unsigned)t & 31u) << 2) | (c << 7);
  gateV<0,1,14,15,13, META.l1mask[14], META.l1role[14]>(Vr, Vi, g, 30, tp4);
  gateV<0,1,14,15,13, META.l1mask[15], META.l1role[15]>(Vr, Vi, g, 31, tp4);

  // Store: amp(k,l) at g = tp4 | (k&3) | (l<<13) | ((k>>2)<<14) -> dwordx4
  #pragma unroll
  for (int l = 0; l < 2; ++l) {
    #pragma unroll
    for (int kh = 0; kh < 4; ++kh) {
      uint4 q;
      q.x = AMPU(Vr[kh*4+0], Vi[kh*4+0], l); q.y = AMPU(Vr[kh*4+1], Vi[kh*4+1], l);
      q.z = AMPU(Vr[kh*4+2], Vi[kh*4+2], l); q.w = AMPU(Vr[kh*4+3], Vi[kh*4+3], l);
      *(uint4*)(stb + (tp4 | ((unsigned)l << 13) | ((unsigned)kh << 14))) = q;
    }
  }
}

// ---------------------------------------------------------------------------
// PASS C: fixed {15,14,13}=f, local {12..0}. k->{7,8,9,10}, lane=6:
// gi21..23 packed, gi24 cross. Then fused Z-expvals (f32 accumulate).
// ---------------------------------------------------------------------------
__global__ KATTR void passC(const unsigned* __restrict__ st,
    const float* __restrict__ g, float* __restrict__ partials) {
  __shared__ float R[4][17];
  const int t = threadIdx.x;
  const int batch = blockIdx.x >> 3;
  const unsigned f = blockIdx.x & 7;
  const unsigned* stb = st + ((size_t)batch << 16);

  // cbase: f->g15..13, t7,t6->g12,g11, t5..t0->g5..0 ; k->g10..7, l->g6
  const unsigned cbase = (f << 13) | (((unsigned)t & 192u) << 5) | ((unsigned)t & 63u);
  h2 Vr[16], Vi[16];
  #pragma unroll
  for (int k = 0; k < 16; ++k) {
    h2 h0 = H2(stb[cbase | ((unsigned)k << 7)]);
    h2 h1 = H2(stb[cbase | ((unsigned)k << 7) | 64u]);
    Vr[k] = (h2){h0.x, h1.x};
    Vi[k] = (h2){h0.y, h1.y};
  }

  gateV<7,8,9,10,6, META.l1mask[5], META.l1role[5]>(Vr, Vi, g, 21, cbase);
  gateV<7,8,9,10,6, META.l1mask[6], META.l1role[6]>(Vr, Vi, g, 22, cbase);
  gateV<7,8,9,10,6, META.l1mask[7], META.l1role[7]>(Vr, Vi, g, 23, cbase);
  gateV<7,8,9,10,6, META.l1mask[8], META.l1role[8]>(Vr, Vi, g, 24, cbase); // cross

  // Packed expvals (f32): reg contribution of (k,l) = (k<<7)|(l<<6)
  v2f sv2[16], tot2 = (v2f){0.f, 0.f};
  #pragma unroll
  for (int w = 0; w < 16; ++w) sv2[w] = (v2f){0.f, 0.f};
  const v2f lm = (v2f){1.f, -1.f};
  #pragma unroll
  for (int k = 0; k < 16; ++k) {
    v2f vr = {(float)Vr[k].x, (float)Vr[k].y};
    v2f vi = {(float)Vi[k].x, (float)Vi[k].y};
    v2f pr = vfma(vi, vi, vr*vr);
    tot2 = tot2 + pr;
    v2f prm = pr * lm;
    #pragma unroll
    for (int w = 0; w < 16; ++w) {
      const unsigned m = META.fin[w];
      const bool fl = ((m >> 6) & 1u) != 0;                               // folds
      const bool sk = (__builtin_popcount(m & ((unsigned)k << 7)) & 1) != 0; // folds
      const v2f term = fl ? prm : pr;
      sv2[w] = sk ? (sv2[w] - term) : (sv2[w] + term);
    }
  }
  float sv[16];
  #pragma unroll
  for (int w = 0; w < 16; ++w) sv[w] = sv2[w].x + sv2[w].y;
  float tot = tot2.x + tot2.y;
  #pragma unroll
  for (int w = 0; w < 16; ++w)
    if (__popc(META.fin[w] & cbase) & 1) sv[w] = -sv[w];   // thread-part sign

  #pragma unroll
  for (int off = 32; off; off >>= 1) {
    tot += __shfl_xor(tot, off, 64);
    #pragma unroll
    for (int w = 0; w < 16; ++w) sv[w] += __shfl_xor(sv[w], off, 64);
  }
  const int wave = t >> 6, lane = t & 63;
  if (lane == 0) {
    #pragma unroll
    for (int w = 0; w < 16; ++w) R[wave][w] = sv[w];
    R[wave][16] = tot;
  }
  __syncthreads();
  if (t < 17) {
    const float s2 = R[0][t] + R[1][t] + R[2][t] + R[3][t];
    partials[(size_t)blockIdx.x * 17 + t] = s2;
  }
}

__global__ __launch_bounds__(64) void head(const float* __restrict__ partials,
    const float* __restrict__ W, const float* __restrict__ bias,
    float* __restrict__ out) {
  const int b = blockIdx.x, tid = threadIdx.x;
  __shared__ float red[17];
  __shared__ float ev[16];
  if (tid < 17) {
    float s = 0.f;
    #pragma unroll
    for (int ch = 0; ch < 8; ++ch) s += partials[(size_t)((b << 3) + ch) * 17 + tid];
    red[tid] = s;
  }
  __syncthreads();
  if (tid < 16) ev[tid] = red[tid] / red[16];
  __syncthreads();
  if (tid < NCLS) {
    float o = bias[tid];
    #pragma unroll
    for (int w = 0; w < 16; ++w) o += ev[w] * W[tid*16 + w];
    out[b*NCLS + tid] = o;
  }
}

extern "C" void kernel_launch(void* const* d_in, const int* in_sizes, int n_in,
                              void* d_out, int out_size, void* d_ws, size_t ws_size,
                              hipStream_t stream) {
  const float* x  = (const float*)d_in[0];   // (256, 65536)
  const float* qp = (const float*)d_in[1];   // (2,16,3)
  const float* W  = (const float*)d_in[2];   // (10,16)
  const float* bv = (const float*)d_in[3];   // (10,)
  float* out = (float*)d_out;                // (256,10) fp32

  // ws: fp16 state (64 MB) | gates (1 KB) | partials (2048*17 floats)
  unsigned* st     = (unsigned*)d_ws;
  float*    gates  = (float*)((char*)d_ws + (size_t)BATCH * 65536 * 4);
  float*    parts  = (float*)((char*)gates + 1024);

  prep_gates<<<dim3(1), dim3(64), 0, stream>>>(qp, gates);
  passA<<<dim3(BATCH*8), dim3(256), 0, stream>>>(x, st, gates);
  passB<<<dim3(BATCH*8), dim3(256), 0, stream>>>(st, gates);
  passC<<<dim3(BATCH*8), dim3(256), 0, stream>>>(st, gates, parts);
  head<<<dim3(BATCH), dim3(64), 0, stream>>>(parts, W, bv, out);
}